// Round 5
// baseline (10369.025 us; speedup 1.0000x reference)
//
#include <hip/hip_runtime.h>

// Problem dims (fixed by reference)
#define T_SEQ 512
#define B_SZ  64
#define IN_SZ 512
#define H_SZ  1024
#define NBLK  256   // 128 blocks layer0 + 128 blocks layer1, 1 block/CU (LDS-forced)
#define NTHR  512   // 8 waves = 4 m-tiles x 2 k-halves

// Per-producer completion flags: one int per block per step, spread 16B apart.
#define FLG_STRIDE 4              // ints per flag slot (16 B)
#define FLG_ROW    (128 * FLG_STRIDE)   // ints per step per layer
#define FLG_LAYER  ((size_t)T_SEQ * FLG_ROW)   // ints per layer region

typedef _Float16 f16;
typedef _Float16 half8 __attribute__((ext_vector_type(8)));
typedef float    f32x4 __attribute__((ext_vector_type(4)));
typedef unsigned long long ull;

// LDS layout: wfrag 128K | P tiles 16KB (16 slots, both k-halves) | c 2KB | bias | hstage
#define SM_WFRAG 0
#define SM_PART  131072
#define SM_C     (131072 + 16384)
#define SM_BIAS  (131072 + 16384 + 2048)
#define SM_STAGE (131072 + 16384 + 2048 + 128)
#define SMEM_BYTES (131072 + 16384 + 2048 + 128 + 1024)

struct Params {
    const float *x;
    const float *wih0, *whh0, *bih0, *bhh0;
    const float *wih1, *whh1, *bih1, *bhh1;
    f16 *h1all;    // [T][B][H]  rotating addresses: consumers use plain cached loads
    f16 *h2all;    // [T][B][H]
    int *flg0, *flg1;   // [T][128*FLG_STRIDE] per-producer flags
};

__device__ __forceinline__ float sigf(float x)     { return 1.f / (1.f + __expf(-x)); }
__device__ __forceinline__ float tanhfast(float x) { return 2.f / (1.f + __expf(-2.f * x)) - 1.f; }

// ---------------------------------------------------------------------------
// INSTRUMENTATION ROUND (R5). Model has sat 2-3x below measurement for 4
// rounds; link-surgery gives noise-level deltas. Bisect empirically:
//   persist_kernel<1> = V_FULL  : exact R2 protocol (best measured, 4973us).
//                                 Runs LAST, produces the real output.
//   persist_kernel<0> = V_NOSYNC: identical, but flag-poll loops compiled out
//                                 (barriers/GEMMs/publish/flag stores kept).
//                                 Free-running -> intra-block serial floor.
// Observables: rocprof top-5 = slower variant's dur; headline dur_us = sum.
// Two equations, two unknowns -> both variants' durations recovered.
// Safety: FULL's dataflow is self-contained (reads only what its own flag
// protocol produced); NOSYNC shares h buffers but uses separate flag rows
// and runs first; it has no waits -> guaranteed termination.
// ---------------------------------------------------------------------------
template<int SYNC>
__global__ __launch_bounds__(NTHR, 2) void persist_kernel(Params p)
{
    extern __shared__ char smem[];
    f16*   wfrag = (f16*)(smem + SM_WFRAG);
    float* P     = (float*)(smem + SM_PART);   // 16 slots x 256 f32, lane-dump layout
    float* c_lds = (float*)(smem + SM_C);      // [64][8] cell state, persistent
    float* bl    = (float*)(smem + SM_BIAS);   // [4 gates][8 cols]
    f16*   hst   = (f16*)(smem + SM_STAGE);    // [64][8] h staging for packed publish

    const int tid = threadIdx.x;
    const int l   = tid & 63, wv = tid >> 6;
    const int n16 = l & 15,  q  = l >> 4;
    const int mt  = wv & 3,  kp = wv >> 2;     // m-tile, k-half
    const int layer = blockIdx.x >> 7;
    const int bid   = blockIdx.x & 127;
    const int jb    = bid * 8;

    // ---- one-time staging: weights fp32 -> f16 fragments in LDS ----
    {
        const int gate0 = n16 >> 3, c8 = n16 & 7;
        const int nfrag = layer ? 128 : 96;   // (K/32)*2
        for (int f = wv; f < nfrag; f += 8) {
            int kstep = f >> 1, nt = f & 1;
            int wrow = (nt * 2 + gate0) * H_SZ + jb + c8;
            const float* src;
            if (layer == 0) {
                src = (kstep < 16) ? p.wih0 + (size_t)wrow * IN_SZ + kstep * 32 + q * 8
                                   : p.whh0 + (size_t)wrow * H_SZ + (kstep - 16) * 32 + q * 8;
            } else {
                src = (kstep < 32) ? p.wih1 + (size_t)wrow * H_SZ + kstep * 32 + q * 8
                                   : p.whh1 + (size_t)wrow * H_SZ + (kstep - 32) * 32 + q * 8;
            }
            half8 hv;
            #pragma unroll
            for (int u = 0; u < 8; ++u) hv[u] = (f16)src[u];
            *(half8*)(wfrag + f * 512 + l * 8) = hv;
        }
        if (tid < 32) {
            int gate = tid >> 3, col = tid & 7;
            int wrow = gate * H_SZ + jb + col;
            bl[tid] = layer ? (p.bih1[wrow] + p.bhh1[wrow])
                            : (p.bih0[wrow] + p.bhh0[wrow]);
        }
        c_lds[tid] = 0.f;   // 512 = 64x8 exactly
    }
    __syncthreads();

    auto ldB = [&](int kg, int nt) -> half8 {
        return *(const half8*)(wfrag + (kg * 2 + nt) * 512 + l * 8);
    };
    auto pollRow = [&](const int* fl) {
        if constexpr (!SYNC) return;
        const int* a0 = fl + l * FLG_STRIDE;
        const int* a1 = fl + (l + 64) * FLG_STRIDE;
        while (true) {
            int va = __hip_atomic_load(a0, __ATOMIC_RELAXED, __HIP_MEMORY_SCOPE_AGENT);
            int vb = __hip_atomic_load(a1, __ATOMIC_RELAXED, __HIP_MEMORY_SCOPE_AGENT);
            if (__all(va & vb)) break;
            __builtin_amdgcn_s_sleep(1);
        }
    };
    auto pollTwo = [&](const int* fA, const int* fB) {
        if constexpr (!SYNC) return;
        const int* a0 = fA + l * FLG_STRIDE;
        const int* a1 = fA + (l + 64) * FLG_STRIDE;
        const int* b0 = fB + l * FLG_STRIDE;
        const int* b1 = fB + (l + 64) * FLG_STRIDE;
        while (true) {
            int va = __hip_atomic_load(a0, __ATOMIC_RELAXED, __HIP_MEMORY_SCOPE_AGENT);
            int vb = __hip_atomic_load(a1, __ATOMIC_RELAXED, __HIP_MEMORY_SCOPE_AGENT);
            int vc = __hip_atomic_load(b0, __ATOMIC_RELAXED, __HIP_MEMORY_SCOPE_AGENT);
            int vd = __hip_atomic_load(b1, __ATOMIC_RELAXED, __HIP_MEMORY_SCOPE_AGENT);
            if (__all(va & vb & vc & vd)) break;
            __builtin_amdgcn_s_sleep(1);
        }
    };
    // R2's finish exactly: merge + epilogue + 128-thread publish + drain
    // barrier + relaxed flag store.
    auto finish = [&](int s, const f32x4& acc0, const f32x4& acc1,
                      f16* dstAll, int* myflg) {
        int slot = kp * 8 + mt * 2;
        *(f32x4*)(P + (slot + 0) * 256 + l * 4) = acc0;
        *(f32x4*)(P + (slot + 1) * 256 + l * 4) = acc1;
        __syncthreads();                       // merge barrier
        {
            int b = tid >> 3, col = tid & 7;
            int bmt = b >> 4, r = b & 15;
            int base = (r >> 2) * 64 + (r & 3);   // lane-dump index of (row r, col 0)
            int s0 = (bmt * 2 + 0) * 256 + base;  // {i,f} tile, kp=0
            int s1 = (bmt * 2 + 1) * 256 + base;  // {g,o} tile, kp=0
            float iv = P[s0 + col * 4]        + P[s0 + 2048 + col * 4]        + bl[col];
            float fv = P[s0 + (col + 8) * 4]  + P[s0 + 2048 + (col + 8) * 4]  + bl[8 + col];
            float gv = P[s1 + col * 4]        + P[s1 + 2048 + col * 4]        + bl[16 + col];
            float ov = P[s1 + (col + 8) * 4]  + P[s1 + 2048 + (col + 8) * 4]  + bl[24 + col];
            float co = c_lds[tid];
            float ii = sigf(iv), ff = sigf(fv), gg = tanhfast(gv), oo = sigf(ov);
            float cn = ff * co + ii * gg;
            float hn = oo * tanhfast(cn);
            c_lds[tid] = cn;
            hst[b * 8 + col] = (f16)hn;
        }
        __syncthreads();
        if (tid < 128) {
            int b = tid >> 1, half = tid & 1;
            ull v = *(const ull*)(hst + b * 8 + half * 4);
            f16* dst = dstAll + (size_t)s * (B_SZ * H_SZ);
            __hip_atomic_store((ull*)(dst + (size_t)b * H_SZ + jb + half * 4), v,
                               __ATOMIC_RELAXED, __HIP_MEMORY_SCOPE_AGENT);
        }
        __syncthreads();   // drain barrier: waitcnt vmcnt(0), all h stores acked
        if (tid == 0)
            __hip_atomic_store(myflg + (size_t)s * FLG_ROW + bid * FLG_STRIDE, 1,
                               __ATOMIC_RELAXED, __HIP_MEMORY_SCOPE_AGENT);
    };

    if (layer == 0) {
        half8 brx0[8], brx1[8], brr0[16], brr1[16];
        #pragma unroll
        for (int u = 0; u < 8; ++u)  { int kg = kp * 8 + u;       brx0[u] = ldB(kg, 0); brx1[u] = ldB(kg, 1); }
        #pragma unroll
        for (int u = 0; u < 16; ++u) { int kg = 16 + kp * 16 + u; brr0[u] = ldB(kg, 0); brr1[u] = ldB(kg, 1); }

        for (int s = 0; s < T_SEQ; ++s) {
            f32x4 acc0 = {}, acc1 = {};
            // -- x part first (no cross-block dep): hides flag propagation
            #pragma unroll
            for (int u = 0; u < 8; ++u) {
                int kb = (kp * 8 + u) * 32 + q * 8;
                const float* ap = p.x + ((size_t)(mt * 16 + n16) * T_SEQ + s) * IN_SZ + kb;
                f32x4 xa = *(const f32x4*)ap;
                f32x4 xb = *(const f32x4*)(ap + 4);
                half8 af;
                #pragma unroll
                for (int u2 = 0; u2 < 4; ++u2) { af[u2] = (f16)xa[u2]; af[4 + u2] = (f16)xb[u2]; }
                acc0 = __builtin_amdgcn_mfma_f32_16x16x32_f16(af, brx0[u], acc0, 0, 0, 0);
                acc1 = __builtin_amdgcn_mfma_f32_16x16x32_f16(af, brx1[u], acc1, 0, 0, 0);
            }
            if (s > 0) {
                if (wv == 0) pollRow(p.flg0 + (size_t)(s - 1) * FLG_ROW);
                __syncthreads();
                // -- recurrent part: h1[s-1], B from registers --
                const f16* hp = p.h1all + (size_t)(s - 1) * (B_SZ * H_SZ)
                              + (size_t)(mt * 16 + n16) * H_SZ + kp * 512 + q * 8;
                #pragma unroll
                for (int u = 0; u < 16; ++u) {
                    half8 af = *(const half8*)(hp + u * 32);
                    acc0 = __builtin_amdgcn_mfma_f32_16x16x32_f16(af, brr0[u], acc0, 0, 0, 0);
                    acc1 = __builtin_amdgcn_mfma_f32_16x16x32_f16(af, brr1[u], acc1, 0, 0, 0);
                }
            }
            finish(s, acc0, acc1, p.h1all, p.flg0);
        }
    } else {
        half8 bri0[16], bri1[16], brr0[8], brr1[8];
        #pragma unroll
        for (int u = 0; u < 16; ++u) { int kg = kp * 16 + u;      bri0[u] = ldB(kg, 0); bri1[u] = ldB(kg, 1); }
        #pragma unroll
        for (int u = 0; u < 8; ++u)  { int kg = 32 + kp * 16 + u; brr0[u] = ldB(kg, 0); brr1[u] = ldB(kg, 1); }

        for (int s = 0; s < T_SEQ; ++s) {
            f32x4 acc0 = {}, acc1 = {};
            if (wv == 0) {
                if (s == 0) pollRow(p.flg0);
                else pollTwo(p.flg0 + (size_t)s * FLG_ROW, p.flg1 + (size_t)(s - 1) * FLG_ROW);
            }
            __syncthreads();
            if (s > 0) {
                // -- recurrent part: h2[s-1] --
                const f16* hp = p.h2all + (size_t)(s - 1) * (B_SZ * H_SZ)
                              + (size_t)(mt * 16 + n16) * H_SZ + kp * 512 + q * 8;
                #pragma unroll
                for (int u = 0; u < 8; ++u) {
                    half8 af = *(const half8*)(hp + u * 32);
                    acc0 = __builtin_amdgcn_mfma_f32_16x16x32_f16(af, brr0[u], acc0, 0, 0, 0);
                    acc1 = __builtin_amdgcn_mfma_f32_16x16x32_f16(af, brr1[u], acc1, 0, 0, 0);
                }
                #pragma unroll
                for (int u = 8; u < 16; ++u) {   // tail B from LDS, latency-shadowed
                    int kg = 32 + kp * 16 + u;
                    half8 b0 = ldB(kg, 0), b1 = ldB(kg, 1);
                    half8 af = *(const half8*)(hp + u * 32);
                    acc0 = __builtin_amdgcn_mfma_f32_16x16x32_f16(af, b0, acc0, 0, 0, 0);
                    acc1 = __builtin_amdgcn_mfma_f32_16x16x32_f16(af, b1, acc1, 0, 0, 0);
                }
            }
            // -- input part: h1[s], B from registers --
            {
                const f16* hp = p.h1all + (size_t)s * (B_SZ * H_SZ)
                              + (size_t)(mt * 16 + n16) * H_SZ + kp * 512 + q * 8;
                #pragma unroll
                for (int u = 0; u < 16; ++u) {
                    half8 af = *(const half8*)(hp + u * 32);
                    acc0 = __builtin_amdgcn_mfma_f32_16x16x32_f16(af, bri0[u], acc0, 0, 0, 0);
                    acc1 = __builtin_amdgcn_mfma_f32_16x16x32_f16(af, bri1[u], acc1, 0, 0, 0);
                }
            }
            finish(s, acc0, acc1, p.h2all, p.flg1);
        }
    }
}

// ---------------------------------------------------------------------------
// Output projection: out[b,t] = h2[t,b,:] . w_out + b_out
// ---------------------------------------------------------------------------
__global__ __launch_bounds__(256) void gemv_kernel(
    const f16* __restrict__ h2all, const float* __restrict__ wout,
    const float* __restrict__ bout, float* __restrict__ out)
{
    int t = blockIdx.x;
    int wave = threadIdx.x >> 6, lane = threadIdx.x & 63;
    float w[16];
    #pragma unroll
    for (int u = 0; u < 16; ++u) w[u] = wout[lane * 16 + u];
    float b0 = bout[0];
    for (int b = wave; b < B_SZ; b += 4) {
        const f16* hp = h2all + ((size_t)t * B_SZ + b) * H_SZ + lane * 16;
        float sum = 0.f;
        #pragma unroll
        for (int u = 0; u < 16; ++u) sum += (float)hp[u] * w[u];
        #pragma unroll
        for (int off = 32; off; off >>= 1) sum += __shfl_down(sum, off, 64);
        if (lane == 0) out[(size_t)b * T_SEQ + t] = sum + b0;
    }
}

// ---------------------------------------------------------------------------
extern "C" void kernel_launch(void* const* d_in, const int* in_sizes, int n_in,
                              void* d_out, int out_size, void* d_ws, size_t ws_size,
                              hipStream_t stream)
{
    const float* x    = (const float*)d_in[0];
    const float* wih0 = (const float*)d_in[1];
    const float* whh0 = (const float*)d_in[2];
    const float* bih0 = (const float*)d_in[3];
    const float* bhh0 = (const float*)d_in[4];
    const float* wih1 = (const float*)d_in[5];
    const float* whh1 = (const float*)d_in[6];
    const float* bih1 = (const float*)d_in[7];
    const float* bhh1 = (const float*)d_in[8];
    const float* wout = (const float*)d_in[9];
    const float* bout = (const float*)d_in[10];
    float* out = (float*)d_out;

    char* ws = (char*)d_ws;
    size_t off = 0;
    auto alloc = [&](size_t bytes) -> void* {
        void* pp = ws + off;
        off += (bytes + 255) & ~(size_t)255;
        return pp;
    };
    f16* h1all = (f16*)alloc((size_t)T_SEQ * B_SZ * H_SZ * 2);     // 67 MB
    f16* h2all = (f16*)alloc((size_t)T_SEQ * B_SZ * H_SZ * 2);     // 67 MB
    // flag regions: [variant][layer]; 2 variants x 2 layers x 1 MB
    const size_t flg_ints = 2 * 2 * FLG_LAYER;
    int* flgs  = (int*)alloc(flg_ints * 4);

    (void)hipMemsetAsync(flgs, 0, flg_ints * 4, stream);  // zero all flags each replay

    Params pa;   // V_FULL (real result)
    pa.x = x;
    pa.wih0 = wih0; pa.whh0 = whh0; pa.bih0 = bih0; pa.bhh0 = bhh0;
    pa.wih1 = wih1; pa.whh1 = whh1; pa.bih1 = bih1; pa.bhh1 = bhh1;
    pa.h1all = h1all; pa.h2all = h2all;
    pa.flg0 = flgs; pa.flg1 = flgs + FLG_LAYER;

    Params pn = pa;  // V_NOSYNC (free-run probe, separate flag rows)
    pn.flg0 = flgs + 2 * FLG_LAYER; pn.flg1 = flgs + 3 * FLG_LAYER;

    (void)hipFuncSetAttribute((const void*)persist_kernel<0>,
                              hipFuncAttributeMaxDynamicSharedMemorySize, SMEM_BYTES);
    (void)hipFuncSetAttribute((const void*)persist_kernel<1>,
                              hipFuncAttributeMaxDynamicSharedMemorySize, SMEM_BYTES);

    hipStreamCaptureStatus cap = hipStreamCaptureStatusNone;
    (void)hipStreamIsCapturing(stream, &cap);

    // --- probe dispatch: V_NOSYNC (free-running, garbage h values, no waits)
    {
        bool launched = false;
        if (cap == hipStreamCaptureStatusNone) {
            void* kargs[] = { (void*)&pn };
            if (hipLaunchCooperativeKernel((const void*)persist_kernel<0>, dim3(NBLK), dim3(NTHR),
                                           kargs, SMEM_BYTES, stream) == hipSuccess)
                launched = true;
        }
        if (!launched)
            persist_kernel<0><<<NBLK, NTHR, SMEM_BYTES, stream>>>(pn);
    }
    // --- real dispatch: V_FULL (R2 protocol; self-contained dataflow)
    {
        bool launched = false;
        if (cap == hipStreamCaptureStatusNone) {
            void* kargs[] = { (void*)&pa };
            if (hipLaunchCooperativeKernel((const void*)persist_kernel<1>, dim3(NBLK), dim3(NTHR),
                                           kargs, SMEM_BYTES, stream) == hipSuccess)
                launched = true;
        }
        if (!launched)
            persist_kernel<1><<<NBLK, NTHR, SMEM_BYTES, stream>>>(pa);
    }

    gemv_kernel<<<T_SEQ, 256, 0, stream>>>(h2all, wout, bout, out);
}

// Round 6
// 4783.234 us; speedup vs baseline: 2.1678x; 2.1678x over previous
//
#include <hip/hip_runtime.h>

// Problem dims (fixed by reference)
#define T_SEQ 512
#define B_SZ  64
#define IN_SZ 512
#define H_SZ  1024
#define NBLK  256   // 128 blocks layer0 + 128 blocks layer1, 1 block/CU (LDS-forced)
#define NTHR  512   // 8 waves = 4 m-tiles x 2 k-halves
#define BH    (B_SZ * H_SZ)

// Per-producer completion flags: one int per block per step, spread 16B apart.
#define FLG_STRIDE 4              // ints per flag slot (16 B)
#define FLG_ROW    (128 * FLG_STRIDE)   // ints per step per layer

typedef _Float16 f16;
typedef _Float16 half8 __attribute__((ext_vector_type(8)));
typedef float    f32x4 __attribute__((ext_vector_type(4)));
typedef unsigned long long ull;

// LDS layout: wfrag 128K | P tiles 16KB (16 slots, both k-halves) | c 2KB | bias | hstage
#define SM_WFRAG 0
#define SM_PART  131072
#define SM_C     (131072 + 16384)
#define SM_BIAS  (131072 + 16384 + 2048)
#define SM_STAGE (131072 + 16384 + 2048 + 128)
#define SMEM_BYTES (131072 + 16384 + 2048 + 128 + 1024)

struct Params {
    const float *x;
    const float *wih0, *whh0, *bih0, *bhh0;
    const float *wih1, *whh1, *bih1, *bhh1;
    f16 *h1all;    // [T][B][H]  rotating addresses: consumers use plain cached loads
    f16 *h2all;    // [T][B][H]
    int *flg0, *flg1;   // [T][128*FLG_STRIDE] per-producer flags
};

__device__ __forceinline__ float sigf(float x)     { return 1.f / (1.f + __expf(-x)); }
__device__ __forceinline__ float tanhfast(float x) { return 2.f / (1.f + __expf(-2.f * x)) - 1.f; }

// ---------------------------------------------------------------------------
// Persistent 2-layer LSTM.
// R6 (post-bisection): R5 proved the wall is INTRA-block (NOSYNC 4960us ~=
// FULL 5370us; sync fabric only ~8%). FETCH arithmetic (512 steps x ~2MB
// 8-XCD re-fetch = 1.02GB ~= measured 1.06GB) proves h loads are LLC-latency
// (~700cy) not L2 (~220cy); the old load->mfma interleave had MLP~2-3 ->
// 32 x 700/2.5 x 2 phases ~= 23k cyc/step = 9.7us. Matches measurement.
// FIX: batch-issue ALL h loads of a step into static register arrays
// (half8 hA[16], hB[16]; vmcnt is issue-ordered so hA[u] is consumable at
// vmcnt(31-u)) -> MLP 16-32, latency paid ~once per step. L0 issues its x
// loads BEFORE the poll (no cross-block dep) so they fly during the wait.
// Sync protocol: exact R2 (verified best): wave0 poll + barrier broadcast,
// 128-thread packed publish, drain barrier, relaxed per-producer flag.
// ---------------------------------------------------------------------------
__global__ __launch_bounds__(NTHR, 2) void persist_kernel(Params p)
{
    extern __shared__ char smem[];
    f16*   wfrag = (f16*)(smem + SM_WFRAG);
    float* P     = (float*)(smem + SM_PART);   // 16 slots x 256 f32, lane-dump layout
    float* c_lds = (float*)(smem + SM_C);      // [64][8] cell state, persistent
    float* bl    = (float*)(smem + SM_BIAS);   // [4 gates][8 cols]
    f16*   hst   = (f16*)(smem + SM_STAGE);    // [64][8] h staging for packed publish

    const int tid = threadIdx.x;
    const int l   = tid & 63, wv = tid >> 6;
    const int n16 = l & 15,  q  = l >> 4;
    const int mt  = wv & 3,  kp = wv >> 2;     // m-tile, k-half
    const int layer = blockIdx.x >> 7;
    const int bid   = blockIdx.x & 127;
    const int jb    = bid * 8;

    // ---- one-time staging: weights fp32 -> f16 fragments in LDS ----
    // frag f = kg*2 + nt; nt=0 holds gates {i,f}, nt=1 holds {g,o} for cols jb..jb+7
    {
        const int gate0 = n16 >> 3, c8 = n16 & 7;
        const int nfrag = layer ? 128 : 96;   // (K/32)*2
        for (int f = wv; f < nfrag; f += 8) {
            int kstep = f >> 1, nt = f & 1;
            int wrow = (nt * 2 + gate0) * H_SZ + jb + c8;
            const float* src;
            if (layer == 0) {
                src = (kstep < 16) ? p.wih0 + (size_t)wrow * IN_SZ + kstep * 32 + q * 8
                                   : p.whh0 + (size_t)wrow * H_SZ + (kstep - 16) * 32 + q * 8;
            } else {
                src = (kstep < 32) ? p.wih1 + (size_t)wrow * H_SZ + kstep * 32 + q * 8
                                   : p.whh1 + (size_t)wrow * H_SZ + (kstep - 32) * 32 + q * 8;
            }
            half8 hv;
            #pragma unroll
            for (int u = 0; u < 8; ++u) hv[u] = (f16)src[u];
            *(half8*)(wfrag + f * 512 + l * 8) = hv;
        }
        if (tid < 32) {
            int gate = tid >> 3, col = tid & 7;
            int wrow = gate * H_SZ + jb + col;
            bl[tid] = layer ? (p.bih1[wrow] + p.bhh1[wrow])
                            : (p.bih0[wrow] + p.bhh0[wrow]);
        }
        c_lds[tid] = 0.f;   // 512 = 64x8 exactly
    }
    __syncthreads();

    auto ldB = [&](int kg, int nt) -> half8 {
        return *(const half8*)(wfrag + (kg * 2 + nt) * 512 + l * 8);
    };
    auto pollRow = [&](const int* fl) {
        const int* a0 = fl + l * FLG_STRIDE;
        const int* a1 = fl + (l + 64) * FLG_STRIDE;
        while (true) {
            int va = __hip_atomic_load(a0, __ATOMIC_RELAXED, __HIP_MEMORY_SCOPE_AGENT);
            int vb = __hip_atomic_load(a1, __ATOMIC_RELAXED, __HIP_MEMORY_SCOPE_AGENT);
            if (__all(va & vb)) break;
            __builtin_amdgcn_s_sleep(1);
        }
    };
    auto pollTwo = [&](const int* fA, const int* fB) {
        const int* a0 = fA + l * FLG_STRIDE;
        const int* a1 = fA + (l + 64) * FLG_STRIDE;
        const int* b0 = fB + l * FLG_STRIDE;
        const int* b1 = fB + (l + 64) * FLG_STRIDE;
        while (true) {
            int va = __hip_atomic_load(a0, __ATOMIC_RELAXED, __HIP_MEMORY_SCOPE_AGENT);
            int vb = __hip_atomic_load(a1, __ATOMIC_RELAXED, __HIP_MEMORY_SCOPE_AGENT);
            int vc = __hip_atomic_load(b0, __ATOMIC_RELAXED, __HIP_MEMORY_SCOPE_AGENT);
            int vd = __hip_atomic_load(b1, __ATOMIC_RELAXED, __HIP_MEMORY_SCOPE_AGENT);
            if (__all(va & vb & vc & vd)) break;
            __builtin_amdgcn_s_sleep(1);
        }
    };
    // R2's finish exactly: merge + epilogue + 128-thread publish + drain
    // barrier + relaxed flag store.
    auto finish = [&](int s, const f32x4& acc0, const f32x4& acc1,
                      f16* dstAll, int* myflg) {
        int slot = kp * 8 + mt * 2;
        *(f32x4*)(P + (slot + 0) * 256 + l * 4) = acc0;
        *(f32x4*)(P + (slot + 1) * 256 + l * 4) = acc1;
        __syncthreads();                       // merge barrier
        {
            int b = tid >> 3, col = tid & 7;
            int bmt = b >> 4, r = b & 15;
            int base = (r >> 2) * 64 + (r & 3);   // lane-dump index of (row r, col 0)
            int s0 = (bmt * 2 + 0) * 256 + base;  // {i,f} tile, kp=0
            int s1 = (bmt * 2 + 1) * 256 + base;  // {g,o} tile, kp=0
            float iv = P[s0 + col * 4]        + P[s0 + 2048 + col * 4]        + bl[col];
            float fv = P[s0 + (col + 8) * 4]  + P[s0 + 2048 + (col + 8) * 4]  + bl[8 + col];
            float gv = P[s1 + col * 4]        + P[s1 + 2048 + col * 4]        + bl[16 + col];
            float ov = P[s1 + (col + 8) * 4]  + P[s1 + 2048 + (col + 8) * 4]  + bl[24 + col];
            float co = c_lds[tid];
            float ii = sigf(iv), ff = sigf(fv), gg = tanhfast(gv), oo = sigf(ov);
            float cn = ff * co + ii * gg;
            float hn = oo * tanhfast(cn);
            c_lds[tid] = cn;
            hst[b * 8 + col] = (f16)hn;
        }
        __syncthreads();
        if (tid < 128) {
            int b = tid >> 1, half = tid & 1;
            ull v = *(const ull*)(hst + b * 8 + half * 4);
            f16* dst = dstAll + (size_t)s * BH;
            __hip_atomic_store((ull*)(dst + (size_t)b * H_SZ + jb + half * 4), v,
                               __ATOMIC_RELAXED, __HIP_MEMORY_SCOPE_AGENT);
        }
        __syncthreads();   // drain barrier: waitcnt vmcnt(0), all h stores acked
        if (tid == 0)
            __hip_atomic_store(myflg + (size_t)s * FLG_ROW + bid * FLG_STRIDE, 1,
                               __ATOMIC_RELAXED, __HIP_MEMORY_SCOPE_AGENT);
    };

    if (layer == 0) {
        for (int s = 0; s < T_SEQ; ++s) {
            // ---- batch-issue x loads BEFORE the poll (no cross-block dep):
            //      16 x f32x4 = 64 VGPRs, all in flight during the wait ----
            f32x4 xl[16];
            #pragma unroll
            for (int u = 0; u < 8; ++u) {
                const float* ap = p.x + ((size_t)(mt * 16 + n16) * T_SEQ + s) * IN_SZ
                                + (kp * 8 + u) * 32 + q * 8;
                xl[2 * u]     = *(const f32x4*)ap;
                xl[2 * u + 1] = *(const f32x4*)(ap + 4);
            }
            f32x4 acc0 = {}, acc1 = {};
            if (s > 0) {
                if (wv == 0) pollRow(p.flg0 + (size_t)(s - 1) * FLG_ROW);
                __syncthreads();
                // ---- batch-issue ALL 16 h loads (64 VGPRs): MLP=16 ----
                const f16* hp = p.h1all + (size_t)(s - 1) * BH
                              + (size_t)(mt * 16 + n16) * H_SZ + kp * 512 + q * 8;
                half8 hl[16];
                #pragma unroll
                for (int u = 0; u < 16; ++u) hl[u] = *(const half8*)(hp + u * 32);
                // x MFMAs run while h loads fly
                #pragma unroll
                for (int u = 0; u < 8; ++u) {
                    half8 af;
                    #pragma unroll
                    for (int u2 = 0; u2 < 4; ++u2) {
                        af[u2]     = (f16)xl[2 * u][u2];
                        af[4 + u2] = (f16)xl[2 * u + 1][u2];
                    }
                    acc0 = __builtin_amdgcn_mfma_f32_16x16x32_f16(af, ldB(kp * 8 + u, 0), acc0, 0, 0, 0);
                    acc1 = __builtin_amdgcn_mfma_f32_16x16x32_f16(af, ldB(kp * 8 + u, 1), acc1, 0, 0, 0);
                }
                // h MFMAs: hl[u] consumable at vmcnt(15-u), progressive overlap
                #pragma unroll
                for (int u = 0; u < 16; ++u) {
                    acc0 = __builtin_amdgcn_mfma_f32_16x16x32_f16(hl[u], ldB(16 + kp * 16 + u, 0), acc0, 0, 0, 0);
                    acc1 = __builtin_amdgcn_mfma_f32_16x16x32_f16(hl[u], ldB(16 + kp * 16 + u, 1), acc1, 0, 0, 0);
                }
            } else {
                #pragma unroll
                for (int u = 0; u < 8; ++u) {
                    half8 af;
                    #pragma unroll
                    for (int u2 = 0; u2 < 4; ++u2) {
                        af[u2]     = (f16)xl[2 * u][u2];
                        af[4 + u2] = (f16)xl[2 * u + 1][u2];
                    }
                    acc0 = __builtin_amdgcn_mfma_f32_16x16x32_f16(af, ldB(kp * 8 + u, 0), acc0, 0, 0, 0);
                    acc1 = __builtin_amdgcn_mfma_f32_16x16x32_f16(af, ldB(kp * 8 + u, 1), acc1, 0, 0, 0);
                }
            }
            finish(s, acc0, acc1, p.h1all, p.flg0);
        }
    } else {
        for (int s = 0; s < T_SEQ; ++s) {
            if (wv == 0) {
                if (s == 0) pollRow(p.flg0);
                else pollTwo(p.flg0 + (size_t)s * FLG_ROW, p.flg1 + (size_t)(s - 1) * FLG_ROW);
            }
            __syncthreads();
            // ---- batch-issue ALL 32 h loads (128 VGPRs): MLP=32, ONE latency
            //      exposure per step. vmcnt is issue-ordered: hA[u] usable at
            //      vmcnt(31-u) while later loads still fly. ----
            const f16* h1p = p.h1all + (size_t)s * BH
                           + (size_t)(mt * 16 + n16) * H_SZ + kp * 512 + q * 8;
            half8 hA[16];
            #pragma unroll
            for (int u = 0; u < 16; ++u) hA[u] = *(const half8*)(h1p + u * 32);
            f32x4 acc0 = {}, acc1 = {};
            if (s > 0) {
                const f16* h2p = p.h2all + (size_t)(s - 1) * BH
                               + (size_t)(mt * 16 + n16) * H_SZ + kp * 512 + q * 8;
                half8 hB[16];
                #pragma unroll
                for (int u = 0; u < 16; ++u) hB[u] = *(const half8*)(h2p + u * 32);
                #pragma unroll
                for (int u = 0; u < 16; ++u) {
                    acc0 = __builtin_amdgcn_mfma_f32_16x16x32_f16(hA[u], ldB(kp * 16 + u, 0), acc0, 0, 0, 0);
                    acc1 = __builtin_amdgcn_mfma_f32_16x16x32_f16(hA[u], ldB(kp * 16 + u, 1), acc1, 0, 0, 0);
                }
                #pragma unroll
                for (int u = 0; u < 16; ++u) {
                    acc0 = __builtin_amdgcn_mfma_f32_16x16x32_f16(hB[u], ldB(32 + kp * 16 + u, 0), acc0, 0, 0, 0);
                    acc1 = __builtin_amdgcn_mfma_f32_16x16x32_f16(hB[u], ldB(32 + kp * 16 + u, 1), acc1, 0, 0, 0);
                }
            } else {
                #pragma unroll
                for (int u = 0; u < 16; ++u) {
                    acc0 = __builtin_amdgcn_mfma_f32_16x16x32_f16(hA[u], ldB(kp * 16 + u, 0), acc0, 0, 0, 0);
                    acc1 = __builtin_amdgcn_mfma_f32_16x16x32_f16(hA[u], ldB(kp * 16 + u, 1), acc1, 0, 0, 0);
                }
            }
            finish(s, acc0, acc1, p.h2all, p.flg1);
        }
    }
}

// ---------------------------------------------------------------------------
// Output projection: out[b,t] = h2[t,b,:] . w_out + b_out
// ---------------------------------------------------------------------------
__global__ __launch_bounds__(256) void gemv_kernel(
    const f16* __restrict__ h2all, const float* __restrict__ wout,
    const float* __restrict__ bout, float* __restrict__ out)
{
    int t = blockIdx.x;
    int wave = threadIdx.x >> 6, lane = threadIdx.x & 63;
    float w[16];
    #pragma unroll
    for (int u = 0; u < 16; ++u) w[u] = wout[lane * 16 + u];
    float b0 = bout[0];
    for (int b = wave; b < B_SZ; b += 4) {
        const f16* hp = h2all + ((size_t)t * B_SZ + b) * H_SZ + lane * 16;
        float sum = 0.f;
        #pragma unroll
        for (int u = 0; u < 16; ++u) sum += (float)hp[u] * w[u];
        #pragma unroll
        for (int off = 32; off; off >>= 1) sum += __shfl_down(sum, off, 64);
        if (lane == 0) out[(size_t)b * T_SEQ + t] = sum + b0;
    }
}

// ---------------------------------------------------------------------------
extern "C" void kernel_launch(void* const* d_in, const int* in_sizes, int n_in,
                              void* d_out, int out_size, void* d_ws, size_t ws_size,
                              hipStream_t stream)
{
    const float* x    = (const float*)d_in[0];
    const float* wih0 = (const float*)d_in[1];
    const float* whh0 = (const float*)d_in[2];
    const float* bih0 = (const float*)d_in[3];
    const float* bhh0 = (const float*)d_in[4];
    const float* wih1 = (const float*)d_in[5];
    const float* whh1 = (const float*)d_in[6];
    const float* bih1 = (const float*)d_in[7];
    const float* bhh1 = (const float*)d_in[8];
    const float* wout = (const float*)d_in[9];
    const float* bout = (const float*)d_in[10];
    float* out = (float*)d_out;

    char* ws = (char*)d_ws;
    size_t off = 0;
    auto alloc = [&](size_t bytes) -> void* {
        void* pp = ws + off;
        off += (bytes + 255) & ~(size_t)255;
        return pp;
    };
    f16* h1all = (f16*)alloc((size_t)T_SEQ * B_SZ * H_SZ * 2);     // 67 MB
    f16* h2all = (f16*)alloc((size_t)T_SEQ * B_SZ * H_SZ * 2);     // 67 MB
    const size_t flg_bytes = (size_t)2 * T_SEQ * FLG_ROW * 4;      // 2 MB
    int* flgs  = (int*)alloc(flg_bytes);

    (void)hipMemsetAsync(flgs, 0, flg_bytes, stream);  // zero flags each replay

    Params pa;
    pa.x = x;
    pa.wih0 = wih0; pa.whh0 = whh0; pa.bih0 = bih0; pa.bhh0 = bhh0;
    pa.wih1 = wih1; pa.whh1 = whh1; pa.bih1 = bih1; pa.bhh1 = bhh1;
    pa.h1all = h1all; pa.h2all = h2all;
    pa.flg0 = flgs; pa.flg1 = flgs + T_SEQ * FLG_ROW;

    (void)hipFuncSetAttribute((const void*)persist_kernel,
                              hipFuncAttributeMaxDynamicSharedMemorySize, SMEM_BYTES);

    // Cooperative launch guarantees co-residency; under graph capture fall back
    // to a plain launch (identical kernel; ~149KB LDS forces 1 block/CU and
    // grid == CU count, so all 256 blocks are co-resident by construction).
    hipStreamCaptureStatus cap = hipStreamCaptureStatusNone;
    (void)hipStreamIsCapturing(stream, &cap);
    bool launched = false;
    if (cap == hipStreamCaptureStatusNone) {
        void* kargs[] = { (void*)&pa };
        if (hipLaunchCooperativeKernel((const void*)persist_kernel, dim3(NBLK), dim3(NTHR),
                                       kargs, SMEM_BYTES, stream) == hipSuccess)
            launched = true;
    }
    if (!launched)
        persist_kernel<<<NBLK, NTHR, SMEM_BYTES, stream>>>(pa);

    gemv_kernel<<<T_SEQ, 256, 0, stream>>>(h2all, wout, bout, out);
}